// Round 1
// baseline (62.713 us; speedup 1.0000x reference)
//
#include <hip/hip_runtime.h>
#include <math.h>

#define IMG      100
#define NPS      50          // patches per side
#define NPATCH   2500        // patches per image
#define NIMG     64
#define NSLICE   4           // slices per image -> 256 blocks, one per CU
#define SLPATCH  (NPATCH / NSLICE)   // 625 patches per slice
#define BLK1     256         // 4 waves per block

// Algebraic collapse of the 4-qubit circuit (verified absmax==0 in R4):
//   e0 = cosq0 cosq4 * cos x0 - sinq4 cosq1 * sin x0 sin x1
//                             - sinq4 sinq1 * sin x0 cos x1
//   e1 = cosq0 * cos x0 * (cosq1 cos x1 - sinq1 sin x1)
//   e2 = cos x2
//   e3 = cosq3 * cos x2 cos x3
// q2, q5 drop out (RZ commutes with every Z it can reach).
//
// Grid: 256 blocks = 64 images x 4 slices. Each block reduces its slice's
// partial dot products with both W rows and writes one float2 to d_ws.
// A trailing 1-block/64-thread kernel combines 4 partials per image,
// adds bias, applies log_softmax.

__global__ __launch_bounds__(BLK1) void quanv_part_kernel(
    const float* __restrict__ x,     // [64,100,100]
    const float* __restrict__ W,     // [2,10000]
    const float* __restrict__ qp,    // [6]
    float2* __restrict__ partial)    // [256] (t0,t1) per block
{
    const int blk = blockIdx.x;
    const int b   = blk >> 2;        // image
    const int s   = blk & 3;         // slice

    // ---- circuit coefficients from q_params (scalar broadcast loads) ----
    const float C0 = __cosf(qp[0]);
    float S1, C1;  __sincosf(qp[1], &S1, &C1);
    const float C3 = __cosf(qp[3]);
    float S4, C4;  __sincosf(qp[4], &S4, &C4);

    const float k_a = C0 * C4;
    const float k_b = S4 * C1;
    const float k_c = S4 * S1;
    const float k_d = C0 * C1;
    const float k_e = C0 * S1;
    const float k_f = C3;

    float t0 = 0.0f, t1 = 0.0f;

    const float* xb = x + b * (IMG * IMG);
    const int p_end = (s + 1) * SLPATCH;

    for (int p = s * SLPATCH + threadIdx.x; p < p_end; p += BLK1) {
        const int pi = p / NPS;           // patch row
        const int pj = p - pi * NPS;      // patch col

        // two float2 loads (row starts even -> 8B aligned)
        const float2 r0 = *reinterpret_cast<const float2*>(xb + (2 * pi) * IMG + 2 * pj);
        const float2 r1 = *reinterpret_cast<const float2*>(xb + (2 * pi + 1) * IMG + 2 * pj);

        float sx0, cz0, sx1, cz1;
        __sincosf(r0.x, &sx0, &cz0);
        __sincosf(r0.y, &sx1, &cz1);
        const float cz2 = __cosf(r1.x);
        const float cz3 = __cosf(r1.y);

        const float e0 = k_a * cz0 - k_b * sx0 * sx1 - k_c * sx0 * cz1;
        const float e1 = k_d * cz0 * cz1 - k_e * cz0 * sx1;
        const float e2 = cz2;
        const float e3 = k_f * cz2 * cz3;

        // ---- dot with W rows (coalesced float4) ----
        const float4 w0 = reinterpret_cast<const float4*>(W)[p];
        const float4 w1 = reinterpret_cast<const float4*>(W)[NPATCH + p];
        t0 += e0 * w0.x + e1 * w0.y + e2 * w0.z + e3 * w0.w;
        t1 += e0 * w1.x + e1 * w1.y + e2 * w1.z + e3 * w1.w;
    }

    // ---- block reduction: wave shuffle, then LDS across 4 waves ----
    #pragma unroll
    for (int off = 32; off > 0; off >>= 1) {
        t0 += __shfl_down(t0, off);
        t1 += __shfl_down(t1, off);
    }
    __shared__ float2 red[BLK1 / 64];
    const int lane = threadIdx.x & 63;
    const int wv   = threadIdx.x >> 6;
    if (lane == 0) red[wv] = make_float2(t0, t1);
    __syncthreads();
    if (threadIdx.x == 0) {
        float a0 = 0.f, a1 = 0.f;
        #pragma unroll
        for (int w = 0; w < BLK1 / 64; ++w) { a0 += red[w].x; a1 += red[w].y; }
        partial[blk] = make_float2(a0, a1);
    }
}

__global__ __launch_bounds__(64) void finalize_kernel(
    const float2* __restrict__ partial,  // [256]
    const float* __restrict__ bias,      // [2]
    float* __restrict__ out)             // [64,2]
{
    const int b = threadIdx.x;           // one image per lane, 64 lanes
    float l0 = bias[0], l1 = bias[1];
    #pragma unroll
    for (int s = 0; s < NSLICE; ++s) {
        const float2 pr = partial[b * NSLICE + s];
        l0 += pr.x;
        l1 += pr.y;
    }
    const float m   = fmaxf(l0, l1);
    const float lse = m + logf(__expf(l0 - m) + __expf(l1 - m));
    out[b * 2 + 0] = l0 - lse;
    out[b * 2 + 1] = l1 - lse;
}

extern "C" void kernel_launch(void* const* d_in, const int* in_sizes, int n_in,
                              void* d_out, int out_size, void* d_ws, size_t ws_size,
                              hipStream_t stream) {
    const float* x    = (const float*)d_in[0];   // [64,100,100]
    const float* W    = (const float*)d_in[1];   // [2,10000]
    const float* bias = (const float*)d_in[2];   // [2]
    const float* qp   = (const float*)d_in[3];   // [6]
    float* out = (float*)d_out;                  // [64,2] fp32

    float2* partial = (float2*)d_ws;             // 256 * 8 B = 2 KB of workspace

    quanv_part_kernel<<<NIMG * NSLICE, BLK1, 0, stream>>>(x, W, qp, partial);
    finalize_kernel<<<1, 64, 0, stream>>>(partial, bias, out);
}

// Round 2
// 60.423 us; speedup vs baseline: 1.0379x; 1.0379x over previous
//
#include <hip/hip_runtime.h>
#include <math.h>

#define IMG      100
#define NPS      50          // patches per side
#define NPAIRS_ROW 25        // horizontal patch-pairs per row
#define NPATCH   2500        // patches per image
#define NPAIR    1250        // patch-pairs per image
#define NIMG     64
#define BLK      1024        // threads per block (16 waves, 4/SIMD)

// One block per image; ONE dispatch total (R1 A/B showed each extra dispatch
// costs ~1.4 us of graph-replay time, dwarfing any kernel-side gain).
//
// Algebraic collapse of the 4-qubit circuit (verified absmax==0):
//   e0 = cosq0 cosq4 * cos x0 - sinq4 cosq1 * sin x0 sin x1
//                             - sinq4 sinq1 * sin x0 cos x1
//   e1 = cosq0 * cos x0 * (cosq1 cos x1 - sinq1 sin x1)
//   e2 = cos x2
//   e3 = cosq3 * cos x2 cos x3
// q2, q5 drop out (RZ commutes with every Z it can reach).
//
// Each thread processes a PAIR of horizontally adjacent patches per
// iteration: x rows load as one float4 each (16B aligned: col start 4*pjj,
// row starts 200*pi and 200*pi+100, all multiples of 4 floats), and the
// two patches' W fragments are 32B contiguous (two adjacent float4s).

__global__ __launch_bounds__(BLK) void quanv_fused_kernel(
    const float* __restrict__ x,     // [64,100,100]
    const float* __restrict__ W,     // [2,10000]
    const float* __restrict__ bias,  // [2]
    const float* __restrict__ qp,    // [6]
    float* __restrict__ out)         // [64,2]
{
    const int b = blockIdx.x;

    // ---- circuit coefficients from q_params (scalar broadcast loads) ----
    const float C0 = __cosf(qp[0]);
    float S1, C1;  __sincosf(qp[1], &S1, &C1);
    const float C3 = __cosf(qp[3]);
    float S4, C4;  __sincosf(qp[4], &S4, &C4);

    const float k_a = C0 * C4;
    const float k_b = S4 * C1;
    const float k_c = S4 * S1;
    const float k_d = C0 * C1;
    const float k_e = C0 * S1;
    const float k_f = C3;

    float t0 = 0.0f, t1 = 0.0f;   // partial dot for logits 0/1

    const float* xb = x + b * (IMG * IMG);
    const float4* W4 = reinterpret_cast<const float4*>(W);

    for (int p2 = threadIdx.x; p2 < NPAIR; p2 += BLK) {
        const int pi  = p2 / NPAIRS_ROW;        // patch row 0..49
        const int pjj = p2 - pi * NPAIRS_ROW;   // pair col 0..24

        // one float4 per image row covers both patches' top/bottom pixels
        const float4 r0 = *reinterpret_cast<const float4*>(xb + (2 * pi) * IMG + 4 * pjj);
        const float4 r1 = *reinterpret_cast<const float4*>(xb + (2 * pi + 1) * IMG + 4 * pjj);

        const int p = pi * NPS + 2 * pjj;       // left patch index
        const float4 w0a = W4[p],          w0b = W4[p + 1];
        const float4 w1a = W4[NPATCH + p], w1b = W4[NPATCH + p + 1];

        // ---- patch A: pixels (r0.x, r0.y, r1.x, r1.y) ----
        {
            float sx0, cz0, sx1, cz1;
            __sincosf(r0.x, &sx0, &cz0);
            __sincosf(r0.y, &sx1, &cz1);
            const float cz2 = __cosf(r1.x);
            const float cz3 = __cosf(r1.y);

            const float e0 = k_a * cz0 - k_b * sx0 * sx1 - k_c * sx0 * cz1;
            const float e1 = k_d * cz0 * cz1 - k_e * cz0 * sx1;
            const float e2 = cz2;
            const float e3 = k_f * cz2 * cz3;

            t0 += e0 * w0a.x + e1 * w0a.y + e2 * w0a.z + e3 * w0a.w;
            t1 += e0 * w1a.x + e1 * w1a.y + e2 * w1a.z + e3 * w1a.w;
        }

        // ---- patch B: pixels (r0.z, r0.w, r1.z, r1.w) ----
        {
            float sx0, cz0, sx1, cz1;
            __sincosf(r0.z, &sx0, &cz0);
            __sincosf(r0.w, &sx1, &cz1);
            const float cz2 = __cosf(r1.z);
            const float cz3 = __cosf(r1.w);

            const float e0 = k_a * cz0 - k_b * sx0 * sx1 - k_c * sx0 * cz1;
            const float e1 = k_d * cz0 * cz1 - k_e * cz0 * sx1;
            const float e2 = cz2;
            const float e3 = k_f * cz2 * cz3;

            t0 += e0 * w0b.x + e1 * w0b.y + e2 * w0b.z + e3 * w0b.w;
            t1 += e0 * w1b.x + e1 * w1b.y + e2 * w1b.z + e3 * w1b.w;
        }
    }

    // ---- block reduction: wave shuffle, then LDS across 16 waves ----
    #pragma unroll
    for (int off = 32; off > 0; off >>= 1) {
        t0 += __shfl_down(t0, off);
        t1 += __shfl_down(t1, off);
    }
    __shared__ float red0[BLK / 64], red1[BLK / 64];
    const int lane = threadIdx.x & 63;
    const int wv   = threadIdx.x >> 6;
    if (lane == 0) { red0[wv] = t0; red1[wv] = t1; }
    __syncthreads();
    if (threadIdx.x == 0) {
        float l0 = 0.f, l1 = 0.f;
        #pragma unroll
        for (int w = 0; w < BLK / 64; ++w) { l0 += red0[w]; l1 += red1[w]; }
        l0 += bias[0];
        l1 += bias[1];
        const float m   = fmaxf(l0, l1);
        const float lse = m + logf(__expf(l0 - m) + __expf(l1 - m));
        out[b * 2 + 0] = l0 - lse;
        out[b * 2 + 1] = l1 - lse;
    }
}

extern "C" void kernel_launch(void* const* d_in, const int* in_sizes, int n_in,
                              void* d_out, int out_size, void* d_ws, size_t ws_size,
                              hipStream_t stream) {
    const float* x    = (const float*)d_in[0];   // [64,100,100]
    const float* W    = (const float*)d_in[1];   // [2,10000]
    const float* bias = (const float*)d_in[2];   // [2]
    const float* qp   = (const float*)d_in[3];   // [6]
    float* out = (float*)d_out;                  // [64,2] fp32

    quanv_fused_kernel<<<NIMG, BLK, 0, stream>>>(x, W, bias, qp, out);
}